// Round 9
// baseline (627.530 us; speedup 1.0000x reference)
//
#include <hip/hip_runtime.h>

#define NN 100000
#define EE 1600000
#define EPSV 1e-5f
#define HN 50000  // node half for agg channel-sharding

using short8 = __attribute__((ext_vector_type(8))) short;
using floatx4 = __attribute__((ext_vector_type(4))) float;

// fp32 -> bf16 round-to-nearest-even
__device__ __forceinline__ unsigned short f2bf(float f) {
    union { float f; unsigned int u; } cv;
    cv.f = f;
    unsigned int u = cv.u;
    u += 0x7FFFu + ((u >> 16) & 1u);
    return (unsigned short)(u >> 16);
}

__device__ __forceinline__ float bf2f(unsigned short u) {
    union { unsigned int i; float f; } cv;
    cv.i = ((unsigned int)u) << 16;
    return cv.f;
}

// ================= degree histogram: per-XCD private copies ===================
__global__ void deg_kernel(const int* __restrict__ dst, int* __restrict__ degi8) {
    int e = blockIdx.x * 256 + threadIdx.x;
    if (e >= EE) return;
    int q = blockIdx.x & 7;
    atomicAdd(&degi8[q * NN + dst[e]], 1);
}

// ================= scan1: sum 8 histogram copies + dinv + block-local prefix ==
__global__ void scan1(const int* __restrict__ degi8, int* __restrict__ degi,
                      int* __restrict__ offsets, int* __restrict__ partial,
                      float* __restrict__ dinv) {
    __shared__ int sdata[256];
    int t = threadIdx.x;
    int n = blockIdx.x * 256 + t;
    int v = 0;
    if (n < NN) {
#pragma unroll
        for (int q = 0; q < 8; ++q) v += degi8[q * NN + n];
        degi[n] = v;
        dinv[n] = rsqrtf((float)v + 1.0f);
    }
    sdata[t] = v;
    __syncthreads();
    for (int off = 1; off < 256; off <<= 1) {
        int x = (t >= off) ? sdata[t - off] : 0;
        __syncthreads();
        sdata[t] += x;
        __syncthreads();
    }
    if (n < NN) offsets[n] = sdata[t] - v;  // block-local exclusive
    if (t == 255) partial[blockIdx.x] = sdata[255];
}

// ================= scan2 + fused stats zeroing ================================
__global__ void scan2(int* __restrict__ partial, int* __restrict__ partial_pref,
                      int nparts, float* __restrict__ stats) {
    __shared__ int sdata[512];
    int t = threadIdx.x;
    if (t < 384) stats[t] = 0.f;  // zero 3 layers x 128 stats (fused memset)
    int v = (t < nparts) ? partial[t] : 0;
    sdata[t] = v;
    __syncthreads();
    for (int off = 1; off < 512; off <<= 1) {
        int x = (t >= off) ? sdata[t - off] : 0;
        __syncthreads();
        sdata[t] += x;
        __syncthreads();
    }
    if (t < nparts) partial_pref[t] = sdata[t] - v;  // exclusive
}

// ================= CSR fill, single pass (proven 84us) ========================
__global__ void fill_kernel(const int* __restrict__ src, const int* __restrict__ dst,
                            int* __restrict__ offsets,
                            const int* __restrict__ partial_pref,
                            const float* __restrict__ dinv,
                            int2* __restrict__ sorted) {
    int e = blockIdx.x * 256 + threadIdx.x;
    if (e >= EE) return;
    int d = dst[e];
    int s = src[e];
    int idx = partial_pref[d >> 8] + atomicAdd(&offsets[d], 1);
    int2 rec;
    rec.x = s;
    rec.y = __float_as_int(dinv[s] * dinv[d]);
    sorted[idx] = rec;
}

// ================= hw(bf16, GROUP-MAJOR) = act(in) @ W via MFMA bf16 =========
// hw layout: [4 groups of 16 channels][NN][16] bf16 -> 3.2MB/group (L2-resident)
__global__ __launch_bounds__(256) void gemm64_bn(const float* __restrict__ in,
                                                 const float* __restrict__ x,
                                                 const float* __restrict__ Win,
                                                 const float* __restrict__ bin,
                                                 const float* __restrict__ stats,
                                                 const float* __restrict__ gamma,
                                                 const float* __restrict__ beta,
                                                 const float* __restrict__ W,
                                                 unsigned short* __restrict__ out,
                                                 int mode) {
    __shared__ __align__(16) unsigned short As[64 * 72];
    __shared__ __align__(16) unsigned short Wt[64 * 72];
    __shared__ float scale[64], shift[64];
    __shared__ float Wins[320];
    __shared__ float bins[64];
    int t = threadIdx.x;
    if (mode == 1) {
        if (t < 64) {
            const float invN = 1.0f / (float)NN;
            float mean = stats[t] * invN;
            float var = stats[64 + t] * invN - mean * mean;
            float rstd = rsqrtf(var + EPSV);
            float sc = gamma[t] * rstd;
            scale[t] = sc;
            shift[t] = beta[t] - mean * sc;
        }
    } else {
        for (int i = t; i < 320; i += 256) Wins[i] = Win[i];
        if (t < 64) bins[t] = bin[t];
    }
    // W^T -> LDS bf16: Wt[c][k] = W[k][c]
    for (int i = t; i < 4096; i += 256) {
        int k = i >> 6, c = i & 63;
        Wt[c * 72 + k] = f2bf(W[k * 64 + c]);
    }
    __syncthreads();
    int base = blockIdx.x * 64;
    if (mode == 1) {
        for (int i = t; i < 4096; i += 256) {
            int r = i >> 6, c = i & 63;
            float v = 0.f;
            if (base + r < NN) {
                v = in[(base + r) * 64 + c];
                v = fmaxf(v * scale[c] + shift[c], 0.f);
            }
            As[r * 72 + c] = f2bf(v);
        }
    } else {
        for (int i = t; i < 4096; i += 256) {
            int r = i >> 6, c = i & 63;
            int n = base + r;
            float v = 0.f;
            if (n < NN) {
                float acc = bins[c];
#pragma unroll
                for (int k = 0; k < 5; ++k) acc += x[n * 5 + k] * Wins[k * 64 + c];
                v = fmaxf(acc, 0.f);
            }
            As[r * 72 + c] = f2bf(v);
        }
    }
    __syncthreads();
    int wv = t >> 6;
    int lane = t & 63;
    int quad = lane >> 4;
    int mm = lane & 15;
    short8 a0 = *(const short8*)&As[(wv * 16 + mm) * 72 + quad * 8];
    short8 a1 = *(const short8*)&As[(wv * 16 + mm) * 72 + 32 + quad * 8];
#pragma unroll
    for (int ct = 0; ct < 4; ++ct) {
        short8 b0 = *(const short8*)&Wt[(ct * 16 + mm) * 72 + quad * 8];
        short8 b1 = *(const short8*)&Wt[(ct * 16 + mm) * 72 + 32 + quad * 8];
        floatx4 acc = {0.f, 0.f, 0.f, 0.f};
        acc = __builtin_amdgcn_mfma_f32_16x16x32_bf16(a0, b0, acc, 0, 0, 0);
        acc = __builtin_amdgcn_mfma_f32_16x16x32_bf16(a1, b1, acc, 0, 0, 0);
#pragma unroll
        for (int reg = 0; reg < 4; ++reg) {
            int n = base + wv * 16 + quad * 4 + reg;
            // group-major: channel c = ct*16+mm lives in group ct
            if (n < NN) out[(ct * NN + n) * 16 + mm] = f2bf(acc[reg]);
        }
    }
}

// ====== CSR gather agg: channel-sharded + software-pipelined rec loads ========
// q=blockIdx&7 -> g=q&3 (16 channels), h=q>>2 (node half). Gathers hit the
// XCD-resident 3.2MB hw slice (L2). The NEXT node's rec chunk (NT, 8B/lane)
// is issued before this node's gathers, hiding the sorted-stream latency.
__global__ __launch_bounds__(256) void agg_kernel(const unsigned int* __restrict__ hw32,
                                                  const int2* __restrict__ sorted,
                                                  const int* __restrict__ offsets,
                                                  const int* __restrict__ partial_pref,
                                                  const int* __restrict__ degi,
                                                  const float* __restrict__ dinv,
                                                  const float* __restrict__ b,
                                                  float* __restrict__ agg,
                                                  float* __restrict__ stats) {
    int t = threadIdx.x;
    int lane = t & 63;
    int w = t >> 6;
    int q = blockIdx.x & 7;
    int g = q & 3;             // channel group: global channels [g*16, g*16+16)
    int h = q >> 2;            // node half
    int bi = blockIdx.x >> 3;  // 0..255
    int eg = lane >> 3;        // edge slot 0..7
    int cu = lane & 7;         // uint within 32B row: channels g*16+2cu, +1
    unsigned gb = (unsigned)g * NN;
    float b0 = b[g * 16 + 2 * cu], b1v = b[g * 16 + 2 * cu + 1];
    float bsx = 0.f, bsy = 0.f, bqx = 0.f, bqy = 0.f;
    int slot = bi * 4 + w;     // 0..1023
    int n0 = h * HN;
    int nend = n0 + HN;
    // ---- preload node 0 of this wave's stripe ----
    int n = n0 + slot;
    int cnt = degi[n];
    int start = partial_pref[n >> 8] + offsets[n] - cnt;
    float di = dinv[n];
    int2 rec = make_int2(0, 0);
    if (lane < min(cnt, 64)) {
        unsigned long long rr =
            __builtin_nontemporal_load((const unsigned long long*)&sorted[start + lane]);
        rec.x = (int)(unsigned int)(rr & 0xffffffffull);
        rec.y = (int)(unsigned int)(rr >> 32);
    }
    while (n < nend) {
        // ---- prefetch node n+1024: meta + first rec chunk (hidden under gathers)
        int nn = n + 1024;
        int cnt2 = 0, start2 = 0;
        float di2 = 0.f;
        int2 rec2 = make_int2(0, 0);
        if (nn < nend) {
            cnt2 = degi[nn];
            start2 = partial_pref[nn >> 8] + offsets[nn] - cnt2;
            di2 = dinv[nn];
            if (lane < min(cnt2, 64)) {
                unsigned long long rr = __builtin_nontemporal_load(
                    (const unsigned long long*)&sorted[start2 + lane]);
                rec2.x = (int)(unsigned int)(rr & 0xffffffffull);
                rec2.y = (int)(unsigned int)(rr >> 32);
            }
        }
        // ---- self-loop ----
        float ax = 0.f, ay = 0.f;
        if (eg == 0) {
            unsigned int u = hw32[(gb + (unsigned)n) * 8 + cu];
            float sc = di * di;
            ax = bf2f((unsigned short)(u & 0xffffu)) * sc + b0;
            ay = bf2f((unsigned short)(u >> 16)) * sc + b1v;
        }
        // ---- gathers for edges 0..min(cnt,64) from the prefetched rec ----
        int m = min(cnt, 64);
        for (int k = 0; k < m; k += 16) {
            int s0 = __shfl(rec.x, k + eg);
            int s1 = __shfl(rec.x, k + 8 + eg);
            unsigned int u0 = hw32[(gb + (unsigned)s0) * 8 + cu];
            unsigned int u1 = hw32[(gb + (unsigned)s1) * 8 + cu];
            float c0 = __int_as_float(__shfl(rec.y, k + eg));
            float c1 = __int_as_float(__shfl(rec.y, k + 8 + eg));
            ax += bf2f((unsigned short)(u0 & 0xffffu)) * c0;
            ay += bf2f((unsigned short)(u0 >> 16)) * c0;
            ax += bf2f((unsigned short)(u1 & 0xffffu)) * c1;
            ay += bf2f((unsigned short)(u1 >> 16)) * c1;
        }
        // ---- rare tail: deg > 64 (serial chunks) ----
        for (int base2 = 64; base2 < cnt; base2 += 64) {
            int m2 = min(64, cnt - base2);
            int2 rc = make_int2(0, 0);
            if (lane < m2) {
                unsigned long long rr = __builtin_nontemporal_load(
                    (const unsigned long long*)&sorted[start + base2 + lane]);
                rc.x = (int)(unsigned int)(rr & 0xffffffffull);
                rc.y = (int)(unsigned int)(rr >> 32);
            }
            for (int k = 0; k < m2; k += 16) {
                int s0 = __shfl(rc.x, k + eg);
                int s1 = __shfl(rc.x, k + 8 + eg);
                unsigned int u0 = hw32[(gb + (unsigned)s0) * 8 + cu];
                unsigned int u1 = hw32[(gb + (unsigned)s1) * 8 + cu];
                float c0 = __int_as_float(__shfl(rc.y, k + eg));
                float c1 = __int_as_float(__shfl(rc.y, k + 8 + eg));
                ax += bf2f((unsigned short)(u0 & 0xffffu)) * c0;
                ay += bf2f((unsigned short)(u0 >> 16)) * c0;
                ax += bf2f((unsigned short)(u1 & 0xffffu)) * c1;
                ay += bf2f((unsigned short)(u1 >> 16)) * c1;
            }
        }
        // ---- reduce over the 8 edge slots (lane bits 3,4,5) ----
        ax += __shfl_xor(ax, 8);
        ay += __shfl_xor(ay, 8);
        ax += __shfl_xor(ax, 16);
        ay += __shfl_xor(ay, 16);
        ax += __shfl_xor(ax, 32);
        ay += __shfl_xor(ay, 32);
        if (eg == 0) {
            // 8 lanes x 8B = one full 64B line per group (no cross-XCD partials)
            *(float2*)&agg[(unsigned)n * 64 + g * 16 + 2 * cu] = make_float2(ax, ay);
            bsx += ax;
            bsy += ay;
            bqx += ax * ax;
            bqy += ay * ay;
        }
        // ---- rotate pipeline state ----
        n = nn;
        cnt = cnt2;
        start = start2;
        di = di2;
        rec = rec2;
    }
    __shared__ float red[2][4][16];
    if (eg == 0) {
        red[0][w][2 * cu] = bsx;
        red[0][w][2 * cu + 1] = bsy;
        red[1][w][2 * cu] = bqx;
        red[1][w][2 * cu + 1] = bqy;
    }
    __syncthreads();
    if (w == 0 && lane < 16) {
        float s = red[0][0][lane] + red[0][1][lane] + red[0][2][lane] + red[0][3][lane];
        float ss = red[1][0][lane] + red[1][1][lane] + red[1][2][lane] + red[1][3][lane];
        atomicAdd(&stats[g * 16 + lane], s);
        atomicAdd(&stats[64 + g * 16 + lane], ss);
    }
}

// ================= classifier: relu(BN(agg)@W1+b1)@W2 + b2, BN fused =========
__global__ __launch_bounds__(256) void classifier(const float* __restrict__ agg,
                                                  const float* __restrict__ stats,
                                                  const float* __restrict__ gamma,
                                                  const float* __restrict__ beta,
                                                  const float* __restrict__ W1,
                                                  const float* __restrict__ b1,
                                                  const float* __restrict__ W2,
                                                  const float* __restrict__ b2,
                                                  float* __restrict__ out) {
    __shared__ float W1s[2048];
    __shared__ float b1s[32];
    __shared__ float W2s[32];
    __shared__ float scale[64], shift[64];
    int t = threadIdx.x;
    for (int i = t; i < 2048; i += 256) W1s[i] = W1[i];
    if (t < 32) {
        b1s[t] = b1[t];
        W2s[t] = W2[t];
    }
    if (t < 64) {
        const float invN = 1.0f / (float)NN;
        float mean = stats[t] * invN;
        float var = stats[64 + t] * invN - mean * mean;
        float rstd = rsqrtf(var + EPSV);
        float sc = gamma[t] * rstd;
        scale[t] = sc;
        shift[t] = beta[t] - mean * sc;
    }
    __syncthreads();
    int n = blockIdx.x * 256 + t;
    if (n >= NN) return;
    float4 h4[16];
    const float4* hp = (const float4*)(agg + n * 64);
#pragma unroll
    for (int i = 0; i < 16; ++i) h4[i] = hp[i];
    float* hr = (float*)h4;
#pragma unroll
    for (int k = 0; k < 64; ++k) hr[k] = fmaxf(hr[k] * scale[k] + shift[k], 0.f);
    float o = b2[0];
    for (int c = 0; c < 32; ++c) {
        float z = b1s[c];
#pragma unroll
        for (int k = 0; k < 64; ++k) z += hr[k] * W1s[k * 32 + c];
        o += fmaxf(z, 0.f) * W2s[c];
    }
    out[n] = o;
}

extern "C" void kernel_launch(void* const* d_in, const int* in_sizes, int n_in,
                              void* d_out, int out_size, void* d_ws, size_t ws_size,
                              hipStream_t stream) {
    const float* x    = (const float*)d_in[0];
    const int*   ei   = (const int*)d_in[1];
    const float* Win  = (const float*)d_in[2];
    const float* bin  = (const float*)d_in[3];
    const float* cW   = (const float*)d_in[4];
    const float* cb   = (const float*)d_in[5];
    const float* gam  = (const float*)d_in[6];
    const float* bet  = (const float*)d_in[7];
    const float* W1   = (const float*)d_in[8];
    const float* b1   = (const float*)d_in[9];
    const float* W2   = (const float*)d_in[10];
    const float* b2   = (const float*)d_in[11];
    float* out = (float*)d_out;

    // ---- workspace layout ----
    unsigned short* hw = (unsigned short*)d_ws;          // NN*64 bf16, group-major [4][NN][16]
    float* agg   = (float*)d_ws + NN * 32;               // NN*64 fp32
    float* dinv  = agg + NN * 64;                        // NN
    float* stats = dinv + NN;                            // 3*128
    int*  degi        = (int*)(stats + 3 * 128);         // NN
    int*  offsets     = degi + NN;                       // NN
    int2* sorted      = (int2*)(offsets + NN);           // EE int2
    int*  partial     = (int*)(sorted + EE);             // 512
    int*  partial_pref = partial + 512;                  // 512
    int*  degi8       = partial_pref + 512;              // 8*NN

    const int* src = ei;
    const int* dst = ei + EE;

    const int NB = (NN + 255) / 256;  // 391
    const int EB = (EE + 255) / 256;  // 6250

    (void)hipMemsetAsync(degi8, 0, 8 * NN * sizeof(int), stream);

    deg_kernel<<<EB, 256, 0, stream>>>(dst, degi8);
    scan1<<<NB, 256, 0, stream>>>(degi8, degi, offsets, partial, dinv);
    scan2<<<1, 512, 0, stream>>>(partial, partial_pref, NB, stats);
    fill_kernel<<<EB, 256, 0, stream>>>(src, dst, offsets, partial_pref, dinv, sorted);

    for (int i = 0; i < 3; ++i) {
        gemm64_bn<<<(NN + 63) / 64, 256, 0, stream>>>(
            agg, x, Win, bin, stats + (i - 1) * 128, gam + (i - 1) * 64,
            bet + (i - 1) * 64, cW + i * 4096, hw, i > 0 ? 1 : 0);
        agg_kernel<<<2048, 256, 0, stream>>>((const unsigned int*)hw, sorted, offsets,
                                             partial_pref, degi, dinv, cb + i * 64, agg,
                                             stats + i * 128);
    }

    classifier<<<(NN + 255) / 256, 256, 0, stream>>>(agg, stats + 2 * 128, gam + 2 * 64,
                                                     bet + 2 * 64, W1, b1, W2, b2, out);
}

// Round 11
// 517.600 us; speedup vs baseline: 1.2124x; 1.2124x over previous
//
#include <hip/hip_runtime.h>

#define NN 100000
#define EE 1600000
#define EPSV 1e-5f

using short8 = __attribute__((ext_vector_type(8))) short;
using floatx4 = __attribute__((ext_vector_type(4))) float;

// fp32 -> bf16 round-to-nearest-even
__device__ __forceinline__ unsigned short f2bf(float f) {
    union { float f; unsigned int u; } cv;
    cv.f = f;
    unsigned int u = cv.u;
    u += 0x7FFFu + ((u >> 16) & 1u);
    return (unsigned short)(u >> 16);
}

__device__ __forceinline__ float bf2f(unsigned short u) {
    union { unsigned int i; float f; } cv;
    cv.i = ((unsigned int)u) << 16;
    return cv.f;
}

// ================= degree histogram: per-XCD private copies ===================
__global__ void deg_kernel(const int* __restrict__ dst, int* __restrict__ degi8) {
    int e = blockIdx.x * 256 + threadIdx.x;
    if (e >= EE) return;
    int q = blockIdx.x & 7;
    atomicAdd(&degi8[q * NN + dst[e]], 1);
}

// ================= scan1: sum 8 histogram copies + dinv + block-local prefix ==
__global__ void scan1(const int* __restrict__ degi8, int* __restrict__ degi,
                      int* __restrict__ offsets, int* __restrict__ partial,
                      float* __restrict__ dinv) {
    __shared__ int sdata[256];
    int t = threadIdx.x;
    int n = blockIdx.x * 256 + t;
    int v = 0;
    if (n < NN) {
#pragma unroll
        for (int q = 0; q < 8; ++q) v += degi8[q * NN + n];
        degi[n] = v;
        dinv[n] = rsqrtf((float)v + 1.0f);
    }
    sdata[t] = v;
    __syncthreads();
    for (int off = 1; off < 256; off <<= 1) {
        int x = (t >= off) ? sdata[t - off] : 0;
        __syncthreads();
        sdata[t] += x;
        __syncthreads();
    }
    if (n < NN) offsets[n] = sdata[t] - v;  // block-local exclusive
    if (t == 255) partial[blockIdx.x] = sdata[255];
}

// ================= scan2 + fused stats zeroing ================================
__global__ void scan2(int* __restrict__ partial, int* __restrict__ partial_pref,
                      int nparts, float* __restrict__ stats) {
    __shared__ int sdata[512];
    int t = threadIdx.x;
    if (t < 384) stats[t] = 0.f;  // zero 3 layers x 128 stats (fused memset)
    int v = (t < nparts) ? partial[t] : 0;
    sdata[t] = v;
    __syncthreads();
    for (int off = 1; off < 512; off <<= 1) {
        int x = (t >= off) ? sdata[t - off] : 0;
        __syncthreads();
        sdata[t] += x;
        __syncthreads();
    }
    if (t < nparts) partial_pref[t] = sdata[t] - v;  // exclusive
}

// ================= CSR fill, single pass (proven 84us; alternatives worse) ====
__global__ void fill_kernel(const int* __restrict__ src, const int* __restrict__ dst,
                            int* __restrict__ offsets,
                            const int* __restrict__ partial_pref,
                            const float* __restrict__ dinv,
                            int2* __restrict__ sorted) {
    int e = blockIdx.x * 256 + threadIdx.x;
    if (e >= EE) return;
    int d = dst[e];
    int s = src[e];
    int idx = partial_pref[d >> 8] + atomicAdd(&offsets[d], 1);
    int2 rec;
    rec.x = s;
    rec.y = __float_as_int(dinv[s] * dinv[d]);
    sorted[idx] = rec;
}

// ================= hw(bf16) = act(in) @ W via MFMA bf16 ======================
__global__ __launch_bounds__(256) void gemm64_bn(const float* __restrict__ in,
                                                 const float* __restrict__ x,
                                                 const float* __restrict__ Win,
                                                 const float* __restrict__ bin,
                                                 const float* __restrict__ stats,
                                                 const float* __restrict__ gamma,
                                                 const float* __restrict__ beta,
                                                 const float* __restrict__ W,
                                                 unsigned short* __restrict__ out,
                                                 int mode) {
    __shared__ __align__(16) unsigned short As[64 * 72];
    __shared__ __align__(16) unsigned short Wt[64 * 72];
    __shared__ float scale[64], shift[64];
    __shared__ float Wins[320];
    __shared__ float bins[64];
    int t = threadIdx.x;
    if (mode == 1) {
        if (t < 64) {
            const float invN = 1.0f / (float)NN;
            float mean = stats[t] * invN;
            float var = stats[64 + t] * invN - mean * mean;
            float rstd = rsqrtf(var + EPSV);
            float sc = gamma[t] * rstd;
            scale[t] = sc;
            shift[t] = beta[t] - mean * sc;
        }
    } else {
        for (int i = t; i < 320; i += 256) Wins[i] = Win[i];
        if (t < 64) bins[t] = bin[t];
    }
    // W^T -> LDS bf16: Wt[c][k] = W[k][c]
    for (int i = t; i < 4096; i += 256) {
        int k = i >> 6, c = i & 63;
        Wt[c * 72 + k] = f2bf(W[k * 64 + c]);
    }
    __syncthreads();
    int base = blockIdx.x * 64;
    if (mode == 1) {
        // float4 global loads (16B/lane, G13); scalar LDS stores (no bank hazard)
        for (int i = t; i < 1024; i += 256) {
            int r = i >> 4, c4 = (i & 15) * 4;
            int n = base + r;
            float4 v = make_float4(0.f, 0.f, 0.f, 0.f);
            if (n < NN) v = *(const float4*)&in[n * 64 + c4];
            As[r * 72 + c4 + 0] = f2bf(fmaxf(v.x * scale[c4 + 0] + shift[c4 + 0], 0.f));
            As[r * 72 + c4 + 1] = f2bf(fmaxf(v.y * scale[c4 + 1] + shift[c4 + 1], 0.f));
            As[r * 72 + c4 + 2] = f2bf(fmaxf(v.z * scale[c4 + 2] + shift[c4 + 2], 0.f));
            As[r * 72 + c4 + 3] = f2bf(fmaxf(v.w * scale[c4 + 3] + shift[c4 + 3], 0.f));
        }
    } else {
        for (int i = t; i < 4096; i += 256) {
            int r = i >> 6, c = i & 63;
            int n = base + r;
            float v = 0.f;
            if (n < NN) {
                float acc = bins[c];
#pragma unroll
                for (int k = 0; k < 5; ++k) acc += x[n * 5 + k] * Wins[k * 64 + c];
                v = fmaxf(acc, 0.f);
            }
            As[r * 72 + c] = f2bf(v);
        }
    }
    __syncthreads();
    int wv = t >> 6;
    int lane = t & 63;
    int quad = lane >> 4;
    int mm = lane & 15;
    short8 a0 = *(const short8*)&As[(wv * 16 + mm) * 72 + quad * 8];
    short8 a1 = *(const short8*)&As[(wv * 16 + mm) * 72 + 32 + quad * 8];
#pragma unroll
    for (int ct = 0; ct < 4; ++ct) {
        short8 b0 = *(const short8*)&Wt[(ct * 16 + mm) * 72 + quad * 8];
        short8 b1 = *(const short8*)&Wt[(ct * 16 + mm) * 72 + 32 + quad * 8];
        floatx4 acc = {0.f, 0.f, 0.f, 0.f};
        acc = __builtin_amdgcn_mfma_f32_16x16x32_bf16(a0, b0, acc, 0, 0, 0);
        acc = __builtin_amdgcn_mfma_f32_16x16x32_bf16(a1, b1, acc, 0, 0, 0);
#pragma unroll
        for (int reg = 0; reg < 4; ++reg) {
            int n = base + wv * 16 + quad * 4 + reg;
            if (n < NN) out[n * 64 + ct * 16 + mm] = f2bf(acc[reg]);
        }
    }
}

// ================= CSR gather aggregation, 4 edges/wave, uint2 gathers ========
// Best measured variant (83.4us/layer). Walled by per-CU outstanding-miss
// capacity x avg miss latency (~3.2M line-requests/layer at the 2-line/row
// floor); 7 restructures (sharding/ILP/NT/prefetch) all landed 80-120us.
__global__ __launch_bounds__(256) void agg_kernel(const uint2* __restrict__ hw64,
                                                  const int2* __restrict__ sorted,
                                                  const int* __restrict__ offsets,
                                                  const int* __restrict__ partial_pref,
                                                  const int* __restrict__ degi,
                                                  const float* __restrict__ dinv,
                                                  const float* __restrict__ b,
                                                  float* __restrict__ agg,
                                                  float* __restrict__ stats) {
    int t = threadIdx.x;
    int lane = t & 63;
    int w = t >> 6;
    int eg = lane >> 4;   // edge slot 0..3
    int cu = lane & 15;   // uint2 index: channels 4cu..4cu+3
    float b0 = b[4 * cu], b1v = b[4 * cu + 1], b2v = b[4 * cu + 2], b3v = b[4 * cu + 3];
    float bs0 = 0.f, bs1 = 0.f, bs2 = 0.f, bs3 = 0.f;
    float bq0 = 0.f, bq1 = 0.f, bq2 = 0.f, bq3 = 0.f;
    for (int n = blockIdx.x * 4 + w; n < NN; n += gridDim.x * 4) {
        int cnt = degi[n];
        int start = partial_pref[n >> 8] + offsets[n] - cnt;  // offsets = local_excl+cnt
        float a0 = 0.f, a1 = 0.f, a2 = 0.f, a3 = 0.f;
        if (eg == 0) {
            uint2 u = hw64[(unsigned)n * 16 + cu];
            float di = dinv[n];
            float sc = di * di;
            a0 = bf2f((unsigned short)(u.x & 0xffffu)) * sc + b0;
            a1 = bf2f((unsigned short)(u.x >> 16)) * sc + b1v;
            a2 = bf2f((unsigned short)(u.y & 0xffffu)) * sc + b2v;
            a3 = bf2f((unsigned short)(u.y >> 16)) * sc + b3v;
        }
        for (int base = 0; base < cnt; base += 64) {
            int m = min(64, cnt - base);
            int2 rec = make_int2(0, 0);  // coef bits 0 -> 0.0f
            if (lane < m) rec = sorted[start + base + lane];
            int k = 0;
            for (; k + 16 <= m; k += 16) {
                int e0 = k + eg, e1 = k + 4 + eg, e2 = k + 8 + eg, e3 = k + 12 + eg;
                int s0 = __shfl(rec.x, e0), s1 = __shfl(rec.x, e1);
                int s2 = __shfl(rec.x, e2), s3 = __shfl(rec.x, e3);
                uint2 u0 = hw64[(unsigned)s0 * 16 + cu];
                uint2 u1 = hw64[(unsigned)s1 * 16 + cu];
                uint2 u2 = hw64[(unsigned)s2 * 16 + cu];
                uint2 u3 = hw64[(unsigned)s3 * 16 + cu];
                float c0 = __int_as_float(__shfl(rec.y, e0));
                float c1 = __int_as_float(__shfl(rec.y, e1));
                float c2 = __int_as_float(__shfl(rec.y, e2));
                float c3 = __int_as_float(__shfl(rec.y, e3));
                a0 += bf2f((unsigned short)(u0.x & 0xffffu)) * c0;
                a1 += bf2f((unsigned short)(u0.x >> 16)) * c0;
                a2 += bf2f((unsigned short)(u0.y & 0xffffu)) * c0;
                a3 += bf2f((unsigned short)(u0.y >> 16)) * c0;
                a0 += bf2f((unsigned short)(u1.x & 0xffffu)) * c1;
                a1 += bf2f((unsigned short)(u1.x >> 16)) * c1;
                a2 += bf2f((unsigned short)(u1.y & 0xffffu)) * c1;
                a3 += bf2f((unsigned short)(u1.y >> 16)) * c1;
                a0 += bf2f((unsigned short)(u2.x & 0xffffu)) * c2;
                a1 += bf2f((unsigned short)(u2.x >> 16)) * c2;
                a2 += bf2f((unsigned short)(u2.y & 0xffffu)) * c2;
                a3 += bf2f((unsigned short)(u2.y >> 16)) * c2;
                a0 += bf2f((unsigned short)(u3.x & 0xffffu)) * c3;
                a1 += bf2f((unsigned short)(u3.x >> 16)) * c3;
                a2 += bf2f((unsigned short)(u3.y & 0xffffu)) * c3;
                a3 += bf2f((unsigned short)(u3.y >> 16)) * c3;
            }
            for (; k + 4 <= m; k += 4) {
                int e = k + eg;
                int s = __shfl(rec.x, e);
                uint2 u = hw64[(unsigned)s * 16 + cu];
                float c = __int_as_float(__shfl(rec.y, e));
                a0 += bf2f((unsigned short)(u.x & 0xffffu)) * c;
                a1 += bf2f((unsigned short)(u.x >> 16)) * c;
                a2 += bf2f((unsigned short)(u.y & 0xffffu)) * c;
                a3 += bf2f((unsigned short)(u.y >> 16)) * c;
            }
            if (k < m) {
                int e = k + eg;  // e may be >= m (< 64): rec there is (0,0) -> coef 0
                int s = __shfl(rec.x, e);
                uint2 u = hw64[(unsigned)s * 16 + cu];
                float c = __int_as_float(__shfl(rec.y, e));
                a0 += bf2f((unsigned short)(u.x & 0xffffu)) * c;
                a1 += bf2f((unsigned short)(u.x >> 16)) * c;
                a2 += bf2f((unsigned short)(u.y & 0xffffu)) * c;
                a3 += bf2f((unsigned short)(u.y >> 16)) * c;
            }
        }
        // reduce over the 4 edge slots (lane bits 4,5)
        a0 += __shfl_xor(a0, 16);
        a1 += __shfl_xor(a1, 16);
        a2 += __shfl_xor(a2, 16);
        a3 += __shfl_xor(a3, 16);
        a0 += __shfl_xor(a0, 32);
        a1 += __shfl_xor(a1, 32);
        a2 += __shfl_xor(a2, 32);
        a3 += __shfl_xor(a3, 32);
        if (eg == 0) {
            float4 v = make_float4(a0, a1, a2, a3);
            *(float4*)&agg[(unsigned)n * 64 + 4 * cu] = v;
            bs0 += a0; bs1 += a1; bs2 += a2; bs3 += a3;
            bq0 += a0 * a0; bq1 += a1 * a1; bq2 += a2 * a2; bq3 += a3 * a3;
        }
    }
    __shared__ float red[2][4][64];
    if (eg == 0) {
        red[0][w][4 * cu] = bs0;
        red[0][w][4 * cu + 1] = bs1;
        red[0][w][4 * cu + 2] = bs2;
        red[0][w][4 * cu + 3] = bs3;
        red[1][w][4 * cu] = bq0;
        red[1][w][4 * cu + 1] = bq1;
        red[1][w][4 * cu + 2] = bq2;
        red[1][w][4 * cu + 3] = bq3;
    }
    __syncthreads();
    if (w == 0) {
        int c = t;  // 0..63
        float s = red[0][0][c] + red[0][1][c] + red[0][2][c] + red[0][3][c];
        float ss = red[1][0][c] + red[1][1][c] + red[1][2][c] + red[1][3][c];
        atomicAdd(&stats[c], s);
        atomicAdd(&stats[64 + c], ss);
    }
}

// ================= classifier: relu(BN(agg)@W1+b1)@W2 + b2, BN fused =========
__global__ __launch_bounds__(256) void classifier(const float* __restrict__ agg,
                                                  const float* __restrict__ stats,
                                                  const float* __restrict__ gamma,
                                                  const float* __restrict__ beta,
                                                  const float* __restrict__ W1,
                                                  const float* __restrict__ b1,
                                                  const float* __restrict__ W2,
                                                  const float* __restrict__ b2,
                                                  float* __restrict__ out) {
    __shared__ float W1s[2048];
    __shared__ float b1s[32];
    __shared__ float W2s[32];
    __shared__ float scale[64], shift[64];
    int t = threadIdx.x;
    for (int i = t; i < 2048; i += 256) W1s[i] = W1[i];
    if (t < 32) {
        b1s[t] = b1[t];
        W2s[t] = W2[t];
    }
    if (t < 64) {
        const float invN = 1.0f / (float)NN;
        float mean = stats[t] * invN;
        float var = stats[64 + t] * invN - mean * mean;
        float rstd = rsqrtf(var + EPSV);
        float sc = gamma[t] * rstd;
        scale[t] = sc;
        shift[t] = beta[t] - mean * sc;
    }
    __syncthreads();
    int n = blockIdx.x * 256 + t;
    if (n >= NN) return;
    float4 h4[16];
    const float4* hp = (const float4*)(agg + n * 64);
#pragma unroll
    for (int i = 0; i < 16; ++i) h4[i] = hp[i];
    float* hr = (float*)h4;
#pragma unroll
    for (int k = 0; k < 64; ++k) hr[k] = fmaxf(hr[k] * scale[k] + shift[k], 0.f);
    float o = b2[0];
    for (int c = 0; c < 32; ++c) {
        float z = b1s[c];
#pragma unroll
        for (int k = 0; k < 64; ++k) z += hr[k] * W1s[k * 32 + c];
        o += fmaxf(z, 0.f) * W2s[c];
    }
    out[n] = o;
}

extern "C" void kernel_launch(void* const* d_in, const int* in_sizes, int n_in,
                              void* d_out, int out_size, void* d_ws, size_t ws_size,
                              hipStream_t stream) {
    const float* x    = (const float*)d_in[0];
    const int*   ei   = (const int*)d_in[1];
    const float* Win  = (const float*)d_in[2];
    const float* bin  = (const float*)d_in[3];
    const float* cW   = (const float*)d_in[4];
    const float* cb   = (const float*)d_in[5];
    const float* gam  = (const float*)d_in[6];
    const float* bet  = (const float*)d_in[7];
    const float* W1   = (const float*)d_in[8];
    const float* b1   = (const float*)d_in[9];
    const float* W2   = (const float*)d_in[10];
    const float* b2   = (const float*)d_in[11];
    float* out = (float*)d_out;

    // ---- workspace layout ----
    unsigned short* hw = (unsigned short*)d_ws;          // NN*64 bf16 (= NN*32 floats)
    float* agg   = (float*)d_ws + NN * 32;               // NN*64 fp32
    float* dinv  = agg + NN * 64;                        // NN
    float* stats = dinv + NN;                            // 3*128
    int*  degi        = (int*)(stats + 3 * 128);         // NN
    int*  offsets     = degi + NN;                       // NN
    int2* sorted      = (int2*)(offsets + NN);           // EE int2
    int*  partial     = (int*)(sorted + EE);             // 512
    int*  partial_pref = partial + 512;                  // 512
    int*  degi8       = partial_pref + 512;              // 8*NN

    const int* src = ei;
    const int* dst = ei + EE;

    const int NB = (NN + 255) / 256;  // 391
    const int EB = (EE + 255) / 256;  // 6250

    (void)hipMemsetAsync(degi8, 0, 8 * NN * sizeof(int), stream);

    deg_kernel<<<EB, 256, 0, stream>>>(dst, degi8);
    scan1<<<NB, 256, 0, stream>>>(degi8, degi, offsets, partial, dinv);
    scan2<<<1, 512, 0, stream>>>(partial, partial_pref, NB, stats);
    fill_kernel<<<EB, 256, 0, stream>>>(src, dst, offsets, partial_pref, dinv, sorted);

    for (int i = 0; i < 3; ++i) {
        gemm64_bn<<<(NN + 63) / 64, 256, 0, stream>>>(
            agg, x, Win, bin, stats + (i - 1) * 128, gam + (i - 1) * 64,
            bet + (i - 1) * 64, cW + i * 4096, hw, i > 0 ? 1 : 0);
        agg_kernel<<<2048, 256, 0, stream>>>((const uint2*)hw, sorted, offsets,
                                             partial_pref, degi, dinv, cb + i * 64, agg,
                                             stats + i * 128);
    }

    classifier<<<(NN + 255) / 256, 256, 0, stream>>>(agg, stats + 2 * 128, gam + 2 * 64,
                                                     bet + 2 * 64, W1, b1, W2, b2, out);
}